// Round 9
// baseline (4215.944 us; speedup 1.0000x reference)
//
#include <hip/hip_runtime.h>

#define N_NODES 100000
#define N_EDGES 3200000
#define N_GRAPHS 64
#define NUM_CLASSES 40
#define DEG_BINS 512
#define NT 4
#define TILE_N 25000  // N_NODES / NT

// ---------------- Tiled CSR build ----------------
// cnt4/rs4 layout: [tile][dst] flat = tile*N_NODES + dst; rs4 has 4N+1 entries.

__global__ void hist_kernel(const int* __restrict__ src, const int* __restrict__ dst,
                            int* __restrict__ cnt4, int n_edges) {
    int idx = blockIdx.x * blockDim.x + threadIdx.x;
    int stride = gridDim.x * blockDim.x;
    for (int e = idx; e < n_edges; e += stride) {
        int s = src[e];
        int t = s / TILE_N;
        atomicAdd(&cnt4[t * N_NODES + dst[e]], 1);
    }
}

// Single-block exclusive scan over n entries. Writes row_start[0..n] and
// leaves a cursor copy in cnt_cursor (consumed by scatter).
__global__ __launch_bounds__(1024) void scan_kernel(int* __restrict__ cnt_cursor,
                                                    int* __restrict__ row_start,
                                                    int n) {
    const int T = 1024;
    int t = threadIdx.x;
    int chunk = (n + T - 1) / T;
    int s = t * chunk;
    int e = min(s + chunk, n);
    int sum = 0;
    for (int i = s; i < e; ++i) sum += cnt_cursor[i];
    __shared__ int tmp[T];
    tmp[t] = sum;
    __syncthreads();
    for (int off = 1; off < T; off <<= 1) {
        int v = (t >= off) ? tmp[t - off] : 0;
        __syncthreads();
        tmp[t] += v;
        __syncthreads();
    }
    int run = tmp[t] - sum;  // exclusive prefix
    for (int i = s; i < e; ++i) {
        int c = cnt_cursor[i];
        row_start[i] = run;
        cnt_cursor[i] = run;
        run += c;
    }
    if (t == T - 1) row_start[n] = run;  // == n_edges
}

__global__ void scatter_kernel(const int* __restrict__ src, const int* __restrict__ dst,
                               int* __restrict__ cursor4, int* __restrict__ col, int n_edges) {
    int idx = blockIdx.x * blockDim.x + threadIdx.x;
    int stride = gridDim.x * blockDim.x;
    for (int e = idx; e < n_edges; e += stride) {
        int s = src[e];
        int t = s / TILE_N;
        int p = atomicAdd(&cursor4[t * N_NODES + dst[e]], 1);
        col[p] = s;
    }
}

// ---------------- Degree-sort permutation (wave load balance) ----------------

__device__ __forceinline__ int total_deg(const int* rs4, int n) {
    int d = 0;
#pragma unroll
    for (int t = 0; t < NT; ++t) d += rs4[t * N_NODES + n + 1] - rs4[t * N_NODES + n];
    return d;
}

__global__ void deg_hist_kernel(const int* __restrict__ rs4, int* __restrict__ dhist,
                                int n_nodes) {
    int n = blockIdx.x * blockDim.x + threadIdx.x;
    if (n >= n_nodes) return;
    atomicAdd(&dhist[min(total_deg(rs4, n), DEG_BINS - 1)], 1);
}

__global__ __launch_bounds__(DEG_BINS) void deg_scan_kernel(const int* __restrict__ dhist,
                                                            int* __restrict__ dcur) {
    __shared__ int tmp[DEG_BINS];
    int t = threadIdx.x;
    int v = dhist[t];
    tmp[t] = v;
    __syncthreads();
    for (int off = 1; off < DEG_BINS; off <<= 1) {
        int u = (t >= off) ? tmp[t - off] : 0;
        __syncthreads();
        tmp[t] += u;
        __syncthreads();
    }
    dcur[t] = tmp[t] - v;  // exclusive
}

__global__ void deg_perm_kernel(const int* __restrict__ rs4, int* __restrict__ dcur,
                                int* __restrict__ perm, int n_nodes) {
    int n = blockIdx.x * blockDim.x + threadIdx.x;
    if (n >= n_nodes) return;
    int p = atomicAdd(&dcur[min(total_deg(rs4, n), DEG_BINS - 1)], 1);
    perm[p] = n;
}

// ---------------- Per-node P/Q precompute ----------------

// Layer A: h = pos (3 dims). P = pos@(W1[0:3]+W1[3:6]); Q = pos@W1[3:6] - b1.
__global__ void pqa_kernel(const float* __restrict__ pos, const float* __restrict__ w1a,
                           const float* __restrict__ b1a,
                           float* __restrict__ P, float* __restrict__ Q, int n_nodes) {
    __shared__ float wtop[3][32], wbot[3][32], sb1[32];
    int t = threadIdx.x;
    if (t < 32) {
        for (int c = 0; c < 3; ++c) {
            wtop[c][t] = w1a[c * 32 + t];
            wbot[c][t] = w1a[(3 + c) * 32 + t];
        }
        sb1[t] = b1a[t];
    }
    __syncthreads();
    int n = blockIdx.x * blockDim.x + t;
    if (n >= n_nodes) return;
    float px = pos[n * 3 + 0], py = pos[n * 3 + 1], pz = pos[n * 3 + 2];
    float pv[32], qv[32];
#pragma unroll
    for (int k = 0; k < 32; ++k) {
        float wb = fmaf(px, wbot[0][k], fmaf(py, wbot[1][k], pz * wbot[2][k]));
        float wt = fmaf(px, wtop[0][k], fmaf(py, wtop[1][k], pz * wtop[2][k]));
        pv[k] = wt + wb;
        qv[k] = wb - sb1[k];
    }
    float4* Pp = (float4*)(P + (size_t)n * 32);
    float4* Qp = (float4*)(Q + (size_t)n * 32);
#pragma unroll
    for (int k = 0; k < 8; ++k) {
        Pp[k] = *(float4*)&pv[k * 4];
        Qp[k] = *(float4*)&qv[k * 4];
    }
}

// Layer B: P = h@W1[0:32] + pos@W1[32:35]; Q = pos@W1[32:35] - b1.
__global__ __launch_bounds__(256) void pqb_kernel(const float* __restrict__ pos,
                                                  const float* __restrict__ H,
                                                  const float* __restrict__ w1b,
                                                  const float* __restrict__ b1b,
                                                  float* __restrict__ P, float* __restrict__ Q,
                                                  int n_nodes) {
    __shared__ float sw[35 * 32];
    __shared__ float sb1[32];
    for (int i = threadIdx.x; i < 35 * 32; i += blockDim.x) sw[i] = w1b[i];
    if (threadIdx.x < 32) sb1[threadIdx.x] = b1b[threadIdx.x];
    __syncthreads();
    int n = blockIdx.x * blockDim.x + threadIdx.x;
    if (n >= n_nodes) return;
    float h[32];
    const float4* Hp = (const float4*)(H + (size_t)n * 32);
#pragma unroll
    for (int k = 0; k < 8; ++k) *(float4*)&h[k * 4] = Hp[k];
    float px = pos[n * 3 + 0], py = pos[n * 3 + 1], pz = pos[n * 3 + 2];
    float pv[32], qv[32];
#pragma unroll
    for (int k = 0; k < 32; ++k) {
        float pd = fmaf(px, sw[32 * 32 + k], fmaf(py, sw[33 * 32 + k], pz * sw[34 * 32 + k]));
        float hd = 0.f;
#pragma unroll
        for (int c = 0; c < 32; ++c) hd = fmaf(h[c], sw[c * 32 + k], hd);
        pv[k] = hd + pd;
        qv[k] = pd - sb1[k];
    }
    float4* Pp = (float4*)(P + (size_t)n * 32);
    float4* Qp = (float4*)(Q + (size_t)n * 32);
#pragma unroll
    for (int k = 0; k < 8; ++k) {
        Pp[k] = *(float4*)&pv[k * 4];
        Qp[k] = *(float4*)&qv[k * 4];
    }
}

// ---------------- Node-centric edge MLP + scatter-max, src-tiled ----------------
// 4 lanes per destination node; lane c owns output channels [8c,8c+8) and
// k-chunk [8c,8c+8) of P/Q rows (quad covers a full 128B row, coalesced).
// Src range is split into NT tiles of TILE_N nodes; each tile's P slice is
// 3.2 MB (fits one XCD's 4 MB L2), and all waves walk tiles in the same
// order, so gathers hit L2 instead of thrashing it. acc lives in registers
// across tiles. 4-edge unroll shares W2 LDS reads; x_k broadcast via DPP
// quad_perm (VALU pipe). Odd tails: duplicate last edge (max idempotent).
// H[n] = max(0, b2 + max_e relu(P[src_e]-Q[n]) @ W2); empty nodes -> 0.

template <int S>
__device__ __forceinline__ float qb(float v) {
#if __has_builtin(__builtin_amdgcn_update_dpp)
    // quad_perm [S,S,S,S]: broadcast lane S of each quad. VALU op.
    int iv = __float_as_int(v);
    return __int_as_float(
        __builtin_amdgcn_update_dpp(iv, iv, S * 0x55, 0xf, 0xf, false));
#else
    return __shfl(v, S, 4);
#endif
}

#define KBLOCK(S, FIRST)                                                       \
    _Pragma("unroll") for (int r = 0; r < 8; ++r) {                            \
        float wv[8];                                                           \
        const float* wr = sw2 + (S * 8 + r) * 32 + c8;                         \
        *(float4*)&wv[0] = *(const float4*)(wr);                               \
        *(float4*)&wv[4] = *(const float4*)(wr + 4);                           \
        float ya = qb<S>(xa[r]);                                               \
        float yb = qb<S>(xb[r]);                                               \
        float yc = qb<S>(xc[r]);                                               \
        float yd = qb<S>(xd[r]);                                               \
        if (FIRST && r == 0) {                                                 \
            _Pragma("unroll") for (int jl = 0; jl < 8; ++jl) {                 \
                ma[jl] = ya * wv[jl];                                          \
                mb[jl] = yb * wv[jl];                                          \
                mc[jl] = yc * wv[jl];                                          \
                md[jl] = yd * wv[jl];                                          \
            }                                                                  \
        } else {                                                               \
            _Pragma("unroll") for (int jl = 0; jl < 8; ++jl) {                 \
                ma[jl] = fmaf(ya, wv[jl], ma[jl]);                             \
                mb[jl] = fmaf(yb, wv[jl], mb[jl]);                             \
                mc[jl] = fmaf(yc, wv[jl], mc[jl]);                             \
                md[jl] = fmaf(yd, wv[jl], md[jl]);                             \
            }                                                                  \
        }                                                                      \
    }

__global__ __launch_bounds__(256, 4) void edge_kernel(const int* __restrict__ perm,
                                                      const int* __restrict__ rs4,
                                                      const int* __restrict__ col,
                                                      const float* __restrict__ P,
                                                      const float* __restrict__ Q,
                                                      const float* __restrict__ w2,
                                                      const float* __restrict__ b2,
                                                      float* __restrict__ H, int n_nodes) {
    __shared__ float sw2[32 * 32];
    __shared__ float sb2[32];
    for (int i = threadIdx.x; i < 32 * 32; i += blockDim.x) sw2[i] = w2[i];
    if (threadIdx.x < 32) sb2[threadIdx.x] = b2[threadIdx.x];
    __syncthreads();
    int gid = (blockIdx.x * blockDim.x + threadIdx.x) >> 2;
    int c = threadIdx.x & 3;
    if (gid >= n_nodes) return;
    int n = perm[gid];
    int c8 = c * 8;

    float q[8];
    {
        const float4* Qp = (const float4*)(Q + (size_t)n * 32 + c8);
        *(float4*)&q[0] = Qp[0];
        *(float4*)&q[4] = Qp[1];
    }
    float acc[8];
#pragma unroll
    for (int j = 0; j < 8; ++j) acc[j] = -3.0e38f;  // bias hoisted; empty -> 0 at end

#pragma unroll
    for (int t = 0; t < NT; ++t) {
        int base = t * N_NODES + n;
        int e0 = rs4[base], e1 = rs4[base + 1];
        for (int e = e0; e < e1; e += 4) {
            int el = e1 - 1;
            int ia = col[e];
            int ib = col[min(e + 1, el)];
            int ic = col[min(e + 2, el)];
            int id = col[min(e + 3, el)];
            float xa[8], xb[8], xc[8], xd[8];
            {
                const float4* Pa = (const float4*)(P + (size_t)ia * 32 + c8);
                const float4* Pb = (const float4*)(P + (size_t)ib * 32 + c8);
                const float4* Pc = (const float4*)(P + (size_t)ic * 32 + c8);
                const float4* Pd = (const float4*)(P + (size_t)id * 32 + c8);
                *(float4*)&xa[0] = Pa[0]; *(float4*)&xa[4] = Pa[1];
                *(float4*)&xb[0] = Pb[0]; *(float4*)&xb[4] = Pb[1];
                *(float4*)&xc[0] = Pc[0]; *(float4*)&xc[4] = Pc[1];
                *(float4*)&xd[0] = Pd[0]; *(float4*)&xd[4] = Pd[1];
            }
#pragma unroll
            for (int r = 0; r < 8; ++r) {
                xa[r] = fmaxf(xa[r] - q[r], 0.f);
                xb[r] = fmaxf(xb[r] - q[r], 0.f);
                xc[r] = fmaxf(xc[r] - q[r], 0.f);
                xd[r] = fmaxf(xd[r] - q[r], 0.f);
            }
            float ma[8], mb[8], mc[8], md[8];
            KBLOCK(0, true)
            KBLOCK(1, false)
            KBLOCK(2, false)
            KBLOCK(3, false)
#pragma unroll
            for (int jl = 0; jl < 8; ++jl)
                acc[jl] = fmaxf(acc[jl], fmaxf(fmaxf(ma[jl], mb[jl]), fmaxf(mc[jl], md[jl])));
        }
    }
    float outv[8];
#pragma unroll
    for (int jl = 0; jl < 8; ++jl) outv[jl] = fmaxf(acc[jl] + sb2[c8 + jl], 0.f);
    float4* Hp = (float4*)(H + (size_t)n * 32 + c8);
    Hp[0] = *(float4*)&outv[0];
    Hp[1] = *(float4*)&outv[4];
}

// ---------------- Global max pool (batch is sorted) ----------------
__global__ __launch_bounds__(256) void pool_kernel(const float* __restrict__ H,
                                                   const int* __restrict__ batch,
                                                   float* __restrict__ gmax, int n_nodes) {
    int g = blockIdx.x;
    int lo = 0, hi = n_nodes;
    while (lo < hi) { int mid = (lo + hi) >> 1; if (batch[mid] < g) lo = mid + 1; else hi = mid; }
    int s = lo;
    lo = 0; hi = n_nodes;
    while (lo < hi) { int mid = (lo + hi) >> 1; if (batch[mid] < g + 1) lo = mid + 1; else hi = mid; }
    int e = lo;

    float acc[32];
#pragma unroll
    for (int ch = 0; ch < 32; ++ch) acc[ch] = 0.f;  // H >= 0; empty graphs -> 0
    for (int n = s + threadIdx.x; n < e; n += blockDim.x) {
        const float4* Hp = (const float4*)(H + (size_t)n * 32);
#pragma unroll
        for (int k = 0; k < 8; ++k) {
            float4 v = Hp[k];
            acc[k * 4 + 0] = fmaxf(acc[k * 4 + 0], v.x);
            acc[k * 4 + 1] = fmaxf(acc[k * 4 + 1], v.y);
            acc[k * 4 + 2] = fmaxf(acc[k * 4 + 2], v.z);
            acc[k * 4 + 3] = fmaxf(acc[k * 4 + 3], v.w);
        }
    }
#pragma unroll
    for (int off = 32; off >= 1; off >>= 1)
#pragma unroll
        for (int ch = 0; ch < 32; ++ch) acc[ch] = fmaxf(acc[ch], __shfl_xor(acc[ch], off));
    __shared__ float red[4][32];
    int wid = threadIdx.x >> 6, lane = threadIdx.x & 63;
    if (lane == 0)
#pragma unroll
        for (int ch = 0; ch < 32; ++ch) red[wid][ch] = acc[ch];
    __syncthreads();
    if (threadIdx.x < 32) {
        int ch = threadIdx.x;
        float v = fmaxf(fmaxf(red[0][ch], red[1][ch]), fmaxf(red[2][ch], red[3][ch]));
        gmax[g * 32 + ch] = v;
    }
}

__global__ void classifier_kernel(const float* __restrict__ gmax, const float* __restrict__ wc,
                                  const float* __restrict__ bc, float* __restrict__ out) {
    int idx = blockIdx.x * blockDim.x + threadIdx.x;
    if (idx >= N_GRAPHS * NUM_CLASSES) return;
    int g = idx / NUM_CLASSES, c = idx % NUM_CLASSES;
    float v = bc[c];
#pragma unroll
    for (int k = 0; k < 32; ++k) v = fmaf(gmax[g * 32 + k], wc[k * NUM_CLASSES + c], v);
    out[idx] = v;
}

// ---------------- Launch ----------------

extern "C" void kernel_launch(void* const* d_in, const int* in_sizes, int n_in,
                              void* d_out, int out_size, void* d_ws, size_t ws_size,
                              hipStream_t stream) {
    const float* pos = (const float*)d_in[0];
    const int* ei = (const int*)d_in[1];
    const int* batch = (const int*)d_in[2];
    const float* w1a = (const float*)d_in[3];
    const float* b1a = (const float*)d_in[4];
    const float* w2a = (const float*)d_in[5];
    const float* b2a = (const float*)d_in[6];
    const float* w1b = (const float*)d_in[7];
    const float* b1b = (const float*)d_in[8];
    const float* w2b = (const float*)d_in[9];
    const float* b2b = (const float*)d_in[10];
    const float* wc = (const float*)d_in[11];
    const float* bc = (const float*)d_in[12];
    float* out = (float*)d_out;

    // workspace layout (~55 MB)
    float* Pbuf = (float*)d_ws;                             // N*32 f32
    float* Qbuf = Pbuf + (size_t)N_NODES * 32;              // N*32 f32
    float* Hbuf = Qbuf + (size_t)N_NODES * 32;              // N*32 f32
    int* rs4 = (int*)(Hbuf + (size_t)N_NODES * 32);         // NT*N+1
    int* cursor4 = rs4 + (NT * N_NODES + 1);                // NT*N (also histogram)
    int* col = cursor4 + NT * N_NODES;                      // E
    int* perm = col + N_EDGES;                              // N
    int* dhist = perm + N_NODES;                            // DEG_BINS
    int* dcur = dhist + DEG_BINS;                           // DEG_BINS
    float* gmax = (float*)(dcur + DEG_BINS);                // 64*32

    const int* srcv = ei;
    const int* dstv = ei + N_EDGES;

    hipMemsetAsync(cursor4, 0, NT * N_NODES * sizeof(int), stream);
    hipMemsetAsync(dhist, 0, DEG_BINS * sizeof(int), stream);
    hist_kernel<<<2048, 256, 0, stream>>>(srcv, dstv, cursor4, N_EDGES);
    scan_kernel<<<1, 1024, 0, stream>>>(cursor4, rs4, NT * N_NODES);
    scatter_kernel<<<2048, 256, 0, stream>>>(srcv, dstv, cursor4, col, N_EDGES);

    int nblk = (N_NODES + 255) / 256;
    deg_hist_kernel<<<nblk, 256, 0, stream>>>(rs4, dhist, N_NODES);
    deg_scan_kernel<<<1, DEG_BINS, 0, stream>>>(dhist, dcur);
    deg_perm_kernel<<<nblk, 256, 0, stream>>>(rs4, dcur, perm, N_NODES);

    int eblk = ((N_NODES * 4) + 255) / 256;
    pqa_kernel<<<nblk, 256, 0, stream>>>(pos, w1a, b1a, Pbuf, Qbuf, N_NODES);
    edge_kernel<<<eblk, 256, 0, stream>>>(perm, rs4, col, Pbuf, Qbuf, w2a, b2a, Hbuf, N_NODES);
    pqb_kernel<<<nblk, 256, 0, stream>>>(pos, Hbuf, w1b, b1b, Pbuf, Qbuf, N_NODES);
    edge_kernel<<<eblk, 256, 0, stream>>>(perm, rs4, col, Pbuf, Qbuf, w2b, b2b, Hbuf, N_NODES);

    pool_kernel<<<N_GRAPHS, 256, 0, stream>>>(Hbuf, batch, gmax, N_NODES);
    classifier_kernel<<<(N_GRAPHS * NUM_CLASSES + 255) / 256, 256, 0, stream>>>(gmax, wc, bc, out);
}

// Round 11
// 2621.110 us; speedup vs baseline: 1.6085x; 1.6085x over previous
//
#include <hip/hip_runtime.h>
#include <hip/hip_fp16.h>

#define N_NODES 100000
#define N_EDGES 3200000
#define N_GRAPHS 64
#define NUM_CLASSES 40
#define DEG_BINS 512

// ---------------- CSR build ----------------

__global__ void hist_kernel(const int* __restrict__ dst, int* __restrict__ cnt, int n_edges) {
    int idx = blockIdx.x * blockDim.x + threadIdx.x;
    int stride = gridDim.x * blockDim.x;
    for (int e = idx; e < n_edges; e += stride)
        atomicAdd(&cnt[dst[e]], 1);
}

// Single-block exclusive scan over node counts. Writes row_start[0..N] and
// cursor copy (consumed by scatter). In-place over cnt.
__global__ __launch_bounds__(1024) void scan_kernel(int* __restrict__ cnt_cursor,
                                                    int* __restrict__ row_start,
                                                    int n_nodes) {
    const int T = 1024;
    int t = threadIdx.x;
    int chunk = (n_nodes + T - 1) / T;
    int s = t * chunk;
    int e = min(s + chunk, n_nodes);
    int sum = 0;
    for (int i = s; i < e; ++i) sum += cnt_cursor[i];
    __shared__ int tmp[T];
    tmp[t] = sum;
    __syncthreads();
    for (int off = 1; off < T; off <<= 1) {
        int v = (t >= off) ? tmp[t - off] : 0;
        __syncthreads();
        tmp[t] += v;
        __syncthreads();
    }
    int run = tmp[t] - sum;  // exclusive prefix
    for (int i = s; i < e; ++i) {
        int c = cnt_cursor[i];
        row_start[i] = run;
        cnt_cursor[i] = run;
        run += c;
    }
    if (t == T - 1) row_start[n_nodes] = run;  // == n_edges
}

__global__ void scatter_kernel(const int* __restrict__ src, const int* __restrict__ dst,
                               int* __restrict__ cursor, int* __restrict__ col, int n_edges) {
    int idx = blockIdx.x * blockDim.x + threadIdx.x;
    int stride = gridDim.x * blockDim.x;
    for (int e = idx; e < n_edges; e += stride) {
        int p = atomicAdd(&cursor[dst[e]], 1);
        col[p] = src[e];
    }
}

// ---------------- Degree-sort permutation (wave load balance) ----------------

__global__ void deg_hist_kernel(const int* __restrict__ row_start, int* __restrict__ dhist,
                                int n_nodes) {
    int n = blockIdx.x * blockDim.x + threadIdx.x;
    if (n >= n_nodes) return;
    int d = row_start[n + 1] - row_start[n];
    atomicAdd(&dhist[min(d, DEG_BINS - 1)], 1);
}

__global__ __launch_bounds__(DEG_BINS) void deg_scan_kernel(const int* __restrict__ dhist,
                                                            int* __restrict__ dcur) {
    __shared__ int tmp[DEG_BINS];
    int t = threadIdx.x;
    int v = dhist[t];
    tmp[t] = v;
    __syncthreads();
    for (int off = 1; off < DEG_BINS; off <<= 1) {
        int u = (t >= off) ? tmp[t - off] : 0;
        __syncthreads();
        tmp[t] += u;
        __syncthreads();
    }
    dcur[t] = tmp[t] - v;  // exclusive
}

__global__ void deg_perm_kernel(const int* __restrict__ row_start, int* __restrict__ dcur,
                                int* __restrict__ perm, int n_nodes) {
    int n = blockIdx.x * blockDim.x + threadIdx.x;
    if (n >= n_nodes) return;
    int d = row_start[n + 1] - row_start[n];
    int p = atomicAdd(&dcur[min(d, DEG_BINS - 1)], 1);
    perm[p] = n;
}

// ---------------- Per-node P/Q precompute ----------------
// P stored fp16 (64B/row) to halve the random-gather bytes in edge_kernel;
// Q and all downstream accumulation stay f32.

// Layer A: h = pos (3 dims). P = pos@(W1[0:3]+W1[3:6]); Q = pos@W1[3:6] - b1.
__global__ void pqa_kernel(const float* __restrict__ pos, const float* __restrict__ w1a,
                           const float* __restrict__ b1a,
                           __half* __restrict__ P, float* __restrict__ Q, int n_nodes) {
    __shared__ float wtop[3][32], wbot[3][32], sb1[32];
    int t = threadIdx.x;
    if (t < 32) {
        for (int c = 0; c < 3; ++c) {
            wtop[c][t] = w1a[c * 32 + t];
            wbot[c][t] = w1a[(3 + c) * 32 + t];
        }
        sb1[t] = b1a[t];
    }
    __syncthreads();
    int n = blockIdx.x * blockDim.x + t;
    if (n >= n_nodes) return;
    float px = pos[n * 3 + 0], py = pos[n * 3 + 1], pz = pos[n * 3 + 2];
    __attribute__((aligned(16))) __half hv[32];
    float qv[32];
#pragma unroll
    for (int k = 0; k < 32; ++k) {
        float wb = fmaf(px, wbot[0][k], fmaf(py, wbot[1][k], pz * wbot[2][k]));
        float wt = fmaf(px, wtop[0][k], fmaf(py, wtop[1][k], pz * wtop[2][k]));
        hv[k] = __float2half_rn(wt + wb);
        qv[k] = wb - sb1[k];
    }
    float4* Pp = (float4*)(P + (size_t)n * 32);  // 64B row
#pragma unroll
    for (int k = 0; k < 4; ++k) Pp[k] = *(float4*)&hv[k * 8];
    float4* Qp = (float4*)(Q + (size_t)n * 32);
#pragma unroll
    for (int k = 0; k < 8; ++k) Qp[k] = *(float4*)&qv[k * 4];
}

// Layer B: P = h@W1[0:32] + pos@W1[32:35]; Q = pos@W1[32:35] - b1.
__global__ __launch_bounds__(256) void pqb_kernel(const float* __restrict__ pos,
                                                  const float* __restrict__ H,
                                                  const float* __restrict__ w1b,
                                                  const float* __restrict__ b1b,
                                                  __half* __restrict__ P, float* __restrict__ Q,
                                                  int n_nodes) {
    __shared__ float sw[35 * 32];
    __shared__ float sb1[32];
    for (int i = threadIdx.x; i < 35 * 32; i += blockDim.x) sw[i] = w1b[i];
    if (threadIdx.x < 32) sb1[threadIdx.x] = b1b[threadIdx.x];
    __syncthreads();
    int n = blockIdx.x * blockDim.x + threadIdx.x;
    if (n >= n_nodes) return;
    float h[32];
    const float4* Hp = (const float4*)(H + (size_t)n * 32);
#pragma unroll
    for (int k = 0; k < 8; ++k) *(float4*)&h[k * 4] = Hp[k];
    float px = pos[n * 3 + 0], py = pos[n * 3 + 1], pz = pos[n * 3 + 2];
    __attribute__((aligned(16))) __half hv[32];
    float qv[32];
#pragma unroll
    for (int k = 0; k < 32; ++k) {
        float pd = fmaf(px, sw[32 * 32 + k], fmaf(py, sw[33 * 32 + k], pz * sw[34 * 32 + k]));
        float hd = 0.f;
#pragma unroll
        for (int c = 0; c < 32; ++c) hd = fmaf(h[c], sw[c * 32 + k], hd);
        hv[k] = __float2half_rn(hd + pd);
        qv[k] = pd - sb1[k];
    }
    float4* Pp = (float4*)(P + (size_t)n * 32);  // 64B row
#pragma unroll
    for (int k = 0; k < 4; ++k) Pp[k] = *(float4*)&hv[k * 8];
    float4* Qp = (float4*)(Q + (size_t)n * 32);
#pragma unroll
    for (int k = 0; k < 8; ++k) Qp[k] = *(float4*)&qv[k * 4];
}

// ---------------- Node-centric edge MLP + scatter-max ----------------
// 4 lanes per destination node; lane c owns output channels [8c,8c+8) and
// k-chunk [8c,8c+8) of P/Q rows. P rows are fp16 (64B), so the quad covers a
// row with ONE 16B load per lane (coalesced 64B). 4-edge unroll shares W2 LDS
// reads; x_k broadcast via DPP quad_perm (VALU pipe). Odd tails: duplicate
// last edge (max idempotent).
// H[n] = max(0, b2 + max_e relu(P[src_e]-Q[n]) @ W2); empty nodes -> 0.

template <int S>
__device__ __forceinline__ float qb(float v) {
#if __has_builtin(__builtin_amdgcn_update_dpp)
    // quad_perm [S,S,S,S]: broadcast lane S of each quad. VALU op.
    int iv = __float_as_int(v);
    return __int_as_float(
        __builtin_amdgcn_update_dpp(iv, iv, S * 0x55, 0xf, 0xf, false));
#else
    return __shfl(v, S, 4);
#endif
}

__device__ __forceinline__ void unpack8(float4 r, float* x) {
    const __half2* h = (const __half2*)&r;
    float2 f;
    f = __half22float2(h[0]); x[0] = f.x; x[1] = f.y;
    f = __half22float2(h[1]); x[2] = f.x; x[3] = f.y;
    f = __half22float2(h[2]); x[4] = f.x; x[5] = f.y;
    f = __half22float2(h[3]); x[6] = f.x; x[7] = f.y;
}

#define KBLOCK(S, FIRST)                                                       \
    _Pragma("unroll") for (int r = 0; r < 8; ++r) {                            \
        float wv[8];                                                           \
        const float* wr = sw2 + (S * 8 + r) * 32 + c8;                         \
        *(float4*)&wv[0] = *(const float4*)(wr);                               \
        *(float4*)&wv[4] = *(const float4*)(wr + 4);                           \
        float ya = qb<S>(xa[r]);                                               \
        float yb = qb<S>(xb[r]);                                               \
        float yc = qb<S>(xc[r]);                                               \
        float yd = qb<S>(xd[r]);                                               \
        if (FIRST && r == 0) {                                                 \
            _Pragma("unroll") for (int jl = 0; jl < 8; ++jl) {                 \
                ma[jl] = ya * wv[jl];                                          \
                mb[jl] = yb * wv[jl];                                          \
                mc[jl] = yc * wv[jl];                                          \
                md[jl] = yd * wv[jl];                                          \
            }                                                                  \
        } else {                                                               \
            _Pragma("unroll") for (int jl = 0; jl < 8; ++jl) {                 \
                ma[jl] = fmaf(ya, wv[jl], ma[jl]);                             \
                mb[jl] = fmaf(yb, wv[jl], mb[jl]);                             \
                mc[jl] = fmaf(yc, wv[jl], mc[jl]);                             \
                md[jl] = fmaf(yd, wv[jl], md[jl]);                             \
            }                                                                  \
        }                                                                      \
    }

__global__ __launch_bounds__(256, 4) void edge_kernel(const int* __restrict__ perm,
                                                      const int* __restrict__ row_start,
                                                      const int* __restrict__ col,
                                                      const __half* __restrict__ P,
                                                      const float* __restrict__ Q,
                                                      const float* __restrict__ w2,
                                                      const float* __restrict__ b2,
                                                      float* __restrict__ H, int n_nodes) {
    __shared__ float sw2[32 * 32];
    __shared__ float sb2[32];
    for (int i = threadIdx.x; i < 32 * 32; i += blockDim.x) sw2[i] = w2[i];
    if (threadIdx.x < 32) sb2[threadIdx.x] = b2[threadIdx.x];
    __syncthreads();
    int gid = (blockIdx.x * blockDim.x + threadIdx.x) >> 2;
    int c = threadIdx.x & 3;
    if (gid >= n_nodes) return;
    int n = perm[gid];
    int c8 = c * 8;

    float q[8];
    {
        const float4* Qp = (const float4*)(Q + (size_t)n * 32 + c8);
        *(float4*)&q[0] = Qp[0];
        *(float4*)&q[4] = Qp[1];
    }
    float acc[8];
#pragma unroll
    for (int j = 0; j < 8; ++j) acc[j] = -3.0e38f;  // bias hoisted; empty -> 0 at end

    int e0 = row_start[n], e1 = row_start[n + 1];
    for (int e = e0; e < e1; e += 4) {
        int el = e1 - 1;
        int ia = col[e];
        int ib = col[min(e + 1, el)];
        int ic = col[min(e + 2, el)];
        int id = col[min(e + 3, el)];
        // one 16B load per lane per edge: fp16 row chunk [8c, 8c+8)
        float4 ra = *(const float4*)(P + (size_t)ia * 32 + c8);
        float4 rb = *(const float4*)(P + (size_t)ib * 32 + c8);
        float4 rc = *(const float4*)(P + (size_t)ic * 32 + c8);
        float4 rd = *(const float4*)(P + (size_t)id * 32 + c8);
        float xa[8], xb[8], xc[8], xd[8];
        unpack8(ra, xa);
        unpack8(rb, xb);
        unpack8(rc, xc);
        unpack8(rd, xd);
#pragma unroll
        for (int r = 0; r < 8; ++r) {
            xa[r] = fmaxf(xa[r] - q[r], 0.f);
            xb[r] = fmaxf(xb[r] - q[r], 0.f);
            xc[r] = fmaxf(xc[r] - q[r], 0.f);
            xd[r] = fmaxf(xd[r] - q[r], 0.f);
        }
        float ma[8], mb[8], mc[8], md[8];
        KBLOCK(0, true)
        KBLOCK(1, false)
        KBLOCK(2, false)
        KBLOCK(3, false)
#pragma unroll
        for (int jl = 0; jl < 8; ++jl)
            acc[jl] = fmaxf(acc[jl], fmaxf(fmaxf(ma[jl], mb[jl]), fmaxf(mc[jl], md[jl])));
    }
    float outv[8];
#pragma unroll
    for (int jl = 0; jl < 8; ++jl) outv[jl] = fmaxf(acc[jl] + sb2[c8 + jl], 0.f);
    float4* Hp = (float4*)(H + (size_t)n * 32 + c8);
    Hp[0] = *(float4*)&outv[0];
    Hp[1] = *(float4*)&outv[4];
}

// ---------------- Global max pool (batch is sorted) ----------------
__global__ __launch_bounds__(256) void pool_kernel(const float* __restrict__ H,
                                                   const int* __restrict__ batch,
                                                   float* __restrict__ gmax, int n_nodes) {
    int g = blockIdx.x;
    int lo = 0, hi = n_nodes;
    while (lo < hi) { int mid = (lo + hi) >> 1; if (batch[mid] < g) lo = mid + 1; else hi = mid; }
    int s = lo;
    lo = 0; hi = n_nodes;
    while (lo < hi) { int mid = (lo + hi) >> 1; if (batch[mid] < g + 1) lo = mid + 1; else hi = mid; }
    int e = lo;

    float acc[32];
#pragma unroll
    for (int ch = 0; ch < 32; ++ch) acc[ch] = 0.f;  // H >= 0; empty graphs -> 0
    for (int n = s + threadIdx.x; n < e; n += blockDim.x) {
        const float4* Hp = (const float4*)(H + (size_t)n * 32);
#pragma unroll
        for (int k = 0; k < 8; ++k) {
            float4 v = Hp[k];
            acc[k * 4 + 0] = fmaxf(acc[k * 4 + 0], v.x);
            acc[k * 4 + 1] = fmaxf(acc[k * 4 + 1], v.y);
            acc[k * 4 + 2] = fmaxf(acc[k * 4 + 2], v.z);
            acc[k * 4 + 3] = fmaxf(acc[k * 4 + 3], v.w);
        }
    }
#pragma unroll
    for (int off = 32; off >= 1; off >>= 1)
#pragma unroll
        for (int ch = 0; ch < 32; ++ch) acc[ch] = fmaxf(acc[ch], __shfl_xor(acc[ch], off));
    __shared__ float red[4][32];
    int wid = threadIdx.x >> 6, lane = threadIdx.x & 63;
    if (lane == 0)
#pragma unroll
        for (int ch = 0; ch < 32; ++ch) red[wid][ch] = acc[ch];
    __syncthreads();
    if (threadIdx.x < 32) {
        int ch = threadIdx.x;
        float v = fmaxf(fmaxf(red[0][ch], red[1][ch]), fmaxf(red[2][ch], red[3][ch]));
        gmax[g * 32 + ch] = v;
    }
}

__global__ void classifier_kernel(const float* __restrict__ gmax, const float* __restrict__ wc,
                                  const float* __restrict__ bc, float* __restrict__ out) {
    int idx = blockIdx.x * blockDim.x + threadIdx.x;
    if (idx >= N_GRAPHS * NUM_CLASSES) return;
    int g = idx / NUM_CLASSES, c = idx % NUM_CLASSES;
    float v = bc[c];
#pragma unroll
    for (int k = 0; k < 32; ++k) v = fmaf(gmax[g * 32 + k], wc[k * NUM_CLASSES + c], v);
    out[idx] = v;
}

// ---------------- Launch ----------------

extern "C" void kernel_launch(void* const* d_in, const int* in_sizes, int n_in,
                              void* d_out, int out_size, void* d_ws, size_t ws_size,
                              hipStream_t stream) {
    const float* pos = (const float*)d_in[0];
    const int* ei = (const int*)d_in[1];
    const int* batch = (const int*)d_in[2];
    const float* w1a = (const float*)d_in[3];
    const float* b1a = (const float*)d_in[4];
    const float* w2a = (const float*)d_in[5];
    const float* b2a = (const float*)d_in[6];
    const float* w1b = (const float*)d_in[7];
    const float* b1b = (const float*)d_in[8];
    const float* w2b = (const float*)d_in[9];
    const float* b2b = (const float*)d_in[10];
    const float* wc = (const float*)d_in[11];
    const float* bc = (const float*)d_in[12];
    float* out = (float*)d_out;

    // workspace layout (~53 MB; P slot kept at f32 size, used as fp16)
    __half* Pbuf = (__half*)d_ws;                           // N*32 fp16 (in N*32-f32 slot)
    float* Qbuf = (float*)d_ws + (size_t)N_NODES * 32;      // N*32 f32
    float* Hbuf = Qbuf + (size_t)N_NODES * 32;              // N*32 f32
    int* row_start = (int*)(Hbuf + (size_t)N_NODES * 32);   // N+1
    int* cursor = row_start + (N_NODES + 1);                // N (also dst histogram)
    int* col = cursor + N_NODES;                            // E
    int* perm = col + N_EDGES;                              // N
    int* dhist = perm + N_NODES;                            // DEG_BINS
    int* dcur = dhist + DEG_BINS;                           // DEG_BINS
    float* gmax = (float*)(dcur + DEG_BINS);                // 64*32

    const int* srcv = ei;
    const int* dstv = ei + N_EDGES;

    hipMemsetAsync(cursor, 0, N_NODES * sizeof(int), stream);
    hipMemsetAsync(dhist, 0, DEG_BINS * sizeof(int), stream);
    hist_kernel<<<2048, 256, 0, stream>>>(dstv, cursor, N_EDGES);
    scan_kernel<<<1, 1024, 0, stream>>>(cursor, row_start, N_NODES);
    scatter_kernel<<<2048, 256, 0, stream>>>(srcv, dstv, cursor, col, N_EDGES);

    int nblk = (N_NODES + 255) / 256;
    deg_hist_kernel<<<nblk, 256, 0, stream>>>(row_start, dhist, N_NODES);
    deg_scan_kernel<<<1, DEG_BINS, 0, stream>>>(dhist, dcur);
    deg_perm_kernel<<<nblk, 256, 0, stream>>>(row_start, dcur, perm, N_NODES);

    int eblk = ((N_NODES * 4) + 255) / 256;
    pqa_kernel<<<nblk, 256, 0, stream>>>(pos, w1a, b1a, Pbuf, Qbuf, N_NODES);
    edge_kernel<<<eblk, 256, 0, stream>>>(perm, row_start, col, Pbuf, Qbuf, w2a, b2a, Hbuf, N_NODES);
    pqb_kernel<<<nblk, 256, 0, stream>>>(pos, Hbuf, w1b, b1b, Pbuf, Qbuf, N_NODES);
    edge_kernel<<<eblk, 256, 0, stream>>>(perm, row_start, col, Pbuf, Qbuf, w2b, b2b, Hbuf, N_NODES);

    pool_kernel<<<N_GRAPHS, 256, 0, stream>>>(Hbuf, batch, gmax, N_NODES);
    classifier_kernel<<<(N_GRAPHS * NUM_CLASSES + 255) / 256, 256, 0, stream>>>(gmax, wc, bc, out);
}